// Round 2
// baseline (523.678 us; speedup 1.0000x reference)
//
#include <hip/hip_runtime.h>

typedef _Float16 v2h __attribute__((ext_vector_type(2)));
typedef _Float16 v4h __attribute__((ext_vector_type(4)));
typedef _Float16 v8h __attribute__((ext_vector_type(8)));
typedef float v4f __attribute__((ext_vector_type(4)));

#define EMB 256
#define VOCAB 50000

// ---------------- helpers ----------------
__device__ __forceinline__ float sigf(float x) {
    return 1.f / (1.f + __expf(-x));
}
__device__ __forceinline__ float tanhf_(float x) {
    float e = __expf(2.f * fabsf(x));
    float th = 1.f - 2.f / (e + 1.f);
    return copysignf(th, x);
}
__device__ __forceinline__ float fdot2_(v2h a, v2h b, float c) {
    return __builtin_amdgcn_fdot2(a, b, c, false);
}

// ---------------- K1: conv/BN stack + feat + gates0 + wsum/bsum ----------------
// block 0: serial conv chain -> feat -> gates0 (all in one block, 512 thr)
// blocks 1..8: wsum = f16(Wih+Whh); block 9: bsum
__global__ __launch_bounds__(512) void k_pre(
        const float* __restrict__ board, const float* __restrict__ conv_w,
        const float* __restrict__ conv_b, const float* __restrict__ gamma,
        const float* __restrict__ beta, const float* __restrict__ p,
        const float* __restrict__ Wlin, const float* __restrict__ blin,
        const float* __restrict__ Wih, const float* __restrict__ bih,
        const float* __restrict__ Whh, const float* __restrict__ bhh,
        _Float16* __restrict__ wsum, float* __restrict__ bsum,
        float* __restrict__ gates0) {
    __shared__ float cur[361];
    __shared__ float feat_s[256];
    __shared__ float red1[8], red2[8], stats[2];
    const int b = blockIdx.x, t = threadIdx.x;
    if (b == 0) {
        const bool act = t < 361;
        const int r = t / 19, c = t % 19;
        float w[9];
#pragma unroll
        for (int k = 0; k < 9; ++k) w[k] = conv_w[k];
        const float cb = conv_b[0], ga = gamma[0], be = beta[0];
        float scales[8] = {p[0], p[1], p[2], p[3], p[4], p[5], p[6], 1.f};
        const int mode[8] = {2, 0, 1, 0, 1, 0, 1, 0};
        if (act) cur[t] = board[t];
        float d2r = 0.f;
        __syncthreads();
#pragma unroll
        for (int it = 0; it < 8; ++it) {
            float y = 0.f;
            if (act) {
#pragma unroll
                for (int di = 0; di < 3; ++di)
#pragma unroll
                    for (int dj = 0; dj < 3; ++dj) {
                        int rr = r + di - 1, cc2 = c + dj - 1;
                        if (rr >= 0 && rr < 19 && cc2 >= 0 && cc2 < 19)
                            y += cur[rr * 19 + cc2] * w[di * 3 + dj];
                    }
                y += cb;
            }
            float s1 = y, s2 = y * y;
            for (int m = 32; m; m >>= 1) {
                s1 += __shfl_xor(s1, m);
                s2 += __shfl_xor(s2, m);
            }
            const int wv = t >> 6;
            if ((t & 63) == 0) { red1[wv] = s1; red2[wv] = s2; }
            __syncthreads();
            if (t == 0) {
                float a = 0.f, b2 = 0.f;
                for (int i = 0; i < 8; ++i) { a += red1[i]; b2 += red2[i]; }
                float mu = a / 361.f;
                float var = b2 / 361.f - mu * mu;
                stats[0] = mu;
                stats[1] = rsqrtf(var + 1e-5f);
            }
            __syncthreads();
            float mu = stats[0], rs = stats[1];
            float v = ga * (y - mu) * rs + be;
            v *= scales[it];
            if (mode[it] == 1) v += d2r;
            v = fmaxf(v, 0.f);
            if (mode[it] != 0) d2r = v;
            if (act) cur[t] = v;
            __syncthreads();
        }
        // ---- feat = Wlin @ d1 + blin (row per 2 threads) ----
        {
            const int fr = t >> 1, fh = t & 1;
            const int k0 = fh ? 184 : 0, k1 = fh ? 361 : 184;
            const float* wrow = Wlin + fr * 361;
            float acc = 0.f;
            for (int k = k0; k < k1; ++k) acc += wrow[k] * cur[k];
            acc += __shfl_xor(acc, 1);
            if (fh == 0) feat_s[fr] = acc + blin[fr];
        }
        __syncthreads();
        // ---- gates0 = Wih @ feat + bih + bhh (2 rows per thread) ----
#pragma unroll
        for (int rr = 0; rr < 2; ++rr) {
            const int row = t + rr * 512;
            const float4* wr4 = (const float4*)(Wih + row * 256);
            float a = 0.f;
            for (int k = 0; k < 64; ++k) {
                float4 wv = wr4[k];
                float4 fv = *(const float4*)(feat_s + k * 4);
                a += wv.x * fv.x + wv.y * fv.y + wv.z * fv.z + wv.w * fv.w;
            }
            gates0[row] = a + bih[row] + bhh[row];
        }
    } else if (b <= 8) {
        const int base = (b - 1) * 32768 + t;
#pragma unroll
        for (int i = 0; i < 64; ++i) {
            int idx = base + i * 512;
            wsum[idx] = (_Float16)(Wih[idx] + Whh[idx]);
        }
    } else {
        for (int i = t; i < 1024; i += 512) bsum[i] = bih[i] + bhh[i];
    }
}

// ---------------- K2: 101-step LSTM chain + concurrent Wdec f32->f16 ----------
// block 0 (512 thr): thread t -> g = t>>2 (cell group), ks = t&3 (k-slice of 64).
// Owns 8 gate rows: cells {g, g+128} x 4 gates, k in [ks*64, ks*64+64).
// First 48 k-elems of each row in VGPRs (asm-pinned), last 16 in swizzled LDS.
// h double-buffered in LDS, 4 slices at stride 144 B (conflict-free b128 reads).
// blocks 1..128: convert Wdec (12.8M f32) to f16 — hidden behind the chain.
__global__ __launch_bounds__(512, 2) void k_lstm(
        const _Float16* __restrict__ wsum, const float* __restrict__ bsum,
        const float* __restrict__ gates0, _Float16* __restrict__ Hg,
        const float* __restrict__ Wdec, _Float16* __restrict__ wdh) {
    if (blockIdx.x != 0) {
        // Wdec f32 -> f16 conversion (grid-stride over 3.2M float4)
        const float4* src = (const float4*)Wdec;
        const int gid = (blockIdx.x - 1) * 512 + threadIdx.x;
        for (int i = gid; i < 3200000; i += 65536) {
            float4 v = src[i];
            v4h o;
            o[0] = (_Float16)v.x; o[1] = (_Float16)v.y;
            o[2] = (_Float16)v.z; o[3] = (_Float16)v.w;
            *(v4h*)(wdh + (size_t)i * 4) = o;
        }
        return;
    }
    extern __shared__ char smem[];
    _Float16* Wl = (_Float16*)smem;          // 131072 B
    char* hb0 = smem + 131072;               // 2 x 576 B double buffer
    const int t = threadIdx.x;
    const int g = t >> 2;
    const int ks = t & 3;
    const int k0 = ks * 64;
    const int sw = (t & 15) << 4;

    int rows[8];
#pragma unroll
    for (int j = 0; j < 4; ++j) { rows[j] = g + 256 * j; rows[j + 4] = g + 128 + 256 * j; }

    // --- register-resident weights: 8 rows x 48 f16 ---
    v2h wr[8][24];
#pragma unroll
    for (int j = 0; j < 8; ++j) {
        const _Float16* src = wsum + rows[j] * 256 + k0;
#pragma unroll
        for (int q6 = 0; q6 < 6; ++q6) {
            float4 fv = *(const float4*)(src + q6 * 8);
            const v2h* vp = (const v2h*)&fv;
            wr[j][q6 * 4 + 0] = vp[0];
            wr[j][q6 * 4 + 1] = vp[1];
            wr[j][q6 * 4 + 2] = vp[2];
            wr[j][q6 * 4 + 3] = vp[3];
        }
    }
    // pin in VGPRs: forbid rematerialization / re-load inside the loop
#pragma unroll
    for (int j = 0; j < 8; ++j)
#pragma unroll
        for (int q = 0; q < 24; ++q)
            asm volatile("" : "+v"(wr[j][q]));

    // --- LDS-resident weights: 8 rows x 16 f16, thread-major 256B, swizzled ---
#pragma unroll
    for (int j = 0; j < 8; ++j) {
        const _Float16* src = wsum + rows[j] * 256 + k0 + 48;
#pragma unroll
        for (int cc = 0; cc < 2; ++cc) {
            float4 fv = *(const float4*)(src + cc * 8);
            const int c = j * 2 + cc;
            *(float4*)((char*)Wl + t * 256 + ((c * 16) ^ sw)) = fv;
        }
    }
    float bsv[8];
#pragma unroll
    for (int j = 0; j < 8; ++j) bsv[j] = bsum[rows[j]];

    const int cell = (ks == 0) ? g : g + 128;            // valid for ks<2
    const int haddr = ((cell >> 6) * 144) + ((cell & 63) * 2);
    float cst = 0.f;
    // --- step 0 from precomputed gates0 ---
    if (ks < 2) {
        float gi = gates0[cell], gg = gates0[cell + 512], go = gates0[cell + 768];
        cst = sigf(gi) * tanhf_(gg);
        float h = sigf(go) * tanhf_(cst);
        *(_Float16*)(hb0 + haddr) = (_Float16)h;
        Hg[cell] = (_Float16)h;
    }
    __syncthreads();

    for (int step = 1; step <= 100; ++step) {
        const char* hr = hb0 + ((step + 1) & 1) * 576;
        char* hw = hb0 + (step & 1) * 576;
        const char* hsl = hr + ks * 144;
        float acc[8];
#pragma unroll
        for (int j = 0; j < 8; ++j) acc[j] = 0.f;
        // register-weight MACs: k in [k0, k0+48)
#pragma unroll
        for (int q = 0; q < 6; ++q) {
            float4 hv = *(const float4*)(hsl + q * 16);
            const v2h* h4 = (const v2h*)&hv;
#pragma unroll
            for (int j = 0; j < 8; ++j) {
#pragma unroll
                for (int u = 0; u < 4; ++u)
                    acc[j] = fdot2_(wr[j][q * 4 + u], h4[u], acc[j]);
            }
        }
        // LDS-weight MACs: k in [k0+48, k0+64)
#pragma unroll
        for (int cc = 0; cc < 2; ++cc) {
            float4 hv = *(const float4*)(hsl + 96 + cc * 16);
            const v2h* h4 = (const v2h*)&hv;
#pragma unroll
            for (int j = 0; j < 8; ++j) {
                const int c = j * 2 + cc;
                float4 wv = *(const float4*)((const char*)Wl + t * 256 + ((c * 16) ^ sw));
                const v2h* w4 = (const v2h*)&wv;
#pragma unroll
                for (int u = 0; u < 4; ++u)
                    acc[j] = fdot2_(w4[u], h4[u], acc[j]);
            }
        }
        // reduce across the 4 k-slices (same wave, lanes t^1, t^2)
#pragma unroll
        for (int j = 0; j < 8; ++j) {
            acc[j] += __shfl_xor(acc[j], 1);
            acc[j] += __shfl_xor(acc[j], 2);
        }
        if (ks < 2) {
            float gi, gf, gg, go;
            if (ks == 0) {
                gi = acc[0] + bsv[0]; gf = acc[1] + bsv[1];
                gg = acc[2] + bsv[2]; go = acc[3] + bsv[3];
            } else {
                gi = acc[4] + bsv[4]; gf = acc[5] + bsv[5];
                gg = acc[6] + bsv[6]; go = acc[7] + bsv[7];
            }
            cst = sigf(gf) * cst + sigf(gi) * tanhf_(gg);
            float h = sigf(go) * tanhf_(cst);
            *(_Float16*)(hw + haddr) = (_Float16)h;
            Hg[step * 256 + cell] = (_Float16)h;
        }
        __syncthreads();
    }
}

// ---------------- K3: logits GEMM [50048x256]x[256x112], f16 Wdec ----------
__global__ __launch_bounds__(256) void k_gemm_f16(
        const _Float16* __restrict__ wdh, const float* __restrict__ bdec,
        const _Float16* __restrict__ Hg, float* __restrict__ out) {
    __shared__ _Float16 Hl[112 * 264];
    const int t = threadIdx.x;
    // zero the N-pad rows 101..111 (cheap insurance)
    {
        float4 z; z.x = 0.f; z.y = 0.f; z.z = 0.f; z.w = 0.f;
        for (int i = t; i < 11 * 33; i += 256) {
            int row = 101 + i / 33, kc = i % 33;
            *(float4*)(Hl + row * 264 + kc * 8) = z;
        }
    }
    // stage H (101 rows x 256 f16)
    for (int i = t; i < 101 * 32; i += 256) {
        int row = i >> 5, kc = i & 31;
        float4 v = ((const float4*)Hg)[i];
        *(float4*)(Hl + row * 264 + kc * 8) = v;
    }
    __syncthreads();

    const int l = t & 63, wv = t >> 6;
    const int mrow = blockIdx.x * 64 + wv * 16 + (l & 15);
    const int mcl = (mrow < VOCAB) ? mrow : (VOCAB - 1);
    const _Float16* arow = wdh + (size_t)mcl * 256 + ((l >> 4) << 3);
    const _Float16* brow = Hl + (l & 15) * 264 + ((l >> 4) << 3);

    v4f acc[7];
#pragma unroll
    for (int nt = 0; nt < 7; ++nt) {
#pragma unroll
        for (int j = 0; j < 4; ++j) acc[nt][j] = 0.f;
    }
#pragma unroll
    for (int ks = 0; ks < 8; ++ks) {
        v8h af = *(const v8h*)(arow + ks * 32);
#pragma unroll
        for (int nt = 0; nt < 7; ++nt) {
            v8h bf = *(const v8h*)(brow + nt * 16 * 264 + ks * 32);
            acc[nt] = __builtin_amdgcn_mfma_f32_16x16x32_f16(af, bf, acc[nt], 0, 0, 0);
        }
    }
    const int rowq = blockIdx.x * 64 + wv * 16 + ((l >> 4) << 2);
    if (rowq < VOCAB) {
        float4 bd = *(const float4*)(bdec + rowq);
#pragma unroll
        for (int nt = 0; nt < 7; ++nt) {
            int tt = nt * 16 + (l & 15);
            if (tt <= 100) {
                float4 v;
                v.x = fmaxf(acc[nt][0] + bd.x, 0.f);
                v.y = fmaxf(acc[nt][1] + bd.y, 0.f);
                v.z = fmaxf(acc[nt][2] + bd.z, 0.f);
                v.w = fmaxf(acc[nt][3] + bd.w, 0.f);
                *(float4*)(out + (size_t)tt * VOCAB + rowq) = v;
            }
        }
    }
}

// ---------------- K3 fallback: f32 Wdec (if workspace too small) ----------
__global__ __launch_bounds__(256) void k_gemm_f32(
        const float* __restrict__ Wdec, const float* __restrict__ bdec,
        const _Float16* __restrict__ Hg, float* __restrict__ out) {
    __shared__ _Float16 Hl[112 * 264];
    const int t = threadIdx.x;
    float4 z; z.x = 0.f; z.y = 0.f; z.z = 0.f; z.w = 0.f;
    for (int i = t; i < 3696; i += 256) ((float4*)Hl)[i] = z;
    __syncthreads();
    for (int i = t; i < 101 * 32; i += 256) {
        int row = i >> 5, kc = i & 31;
        float4 v = ((const float4*)Hg)[i];
        *(float4*)(Hl + row * 264 + kc * 8) = v;
    }
    __syncthreads();
    const int l = t & 63, wv = t >> 6;
    const int mrow = blockIdx.x * 64 + wv * 16 + (l & 15);
    const int mcl = (mrow < VOCAB) ? mrow : (VOCAB - 1);
    const float* arow = Wdec + (size_t)mcl * 256 + ((l >> 4) << 3);
    const _Float16* brow = Hl + (l & 15) * 264 + ((l >> 4) << 3);
    v4f acc[7];
#pragma unroll
    for (int nt = 0; nt < 7; ++nt) {
#pragma unroll
        for (int j = 0; j < 4; ++j) acc[nt][j] = 0.f;
    }
#pragma unroll
    for (int ks = 0; ks < 8; ++ks) {
        float4 a0 = *(const float4*)(arow + ks * 32);
        float4 a1 = *(const float4*)(arow + ks * 32 + 4);
        v8h af;
        af[0] = (_Float16)a0.x; af[1] = (_Float16)a0.y;
        af[2] = (_Float16)a0.z; af[3] = (_Float16)a0.w;
        af[4] = (_Float16)a1.x; af[5] = (_Float16)a1.y;
        af[6] = (_Float16)a1.z; af[7] = (_Float16)a1.w;
#pragma unroll
        for (int nt = 0; nt < 7; ++nt) {
            v8h bf = *(const v8h*)(brow + nt * 16 * 264 + ks * 32);
            acc[nt] = __builtin_amdgcn_mfma_f32_16x16x32_f16(af, bf, acc[nt], 0, 0, 0);
        }
    }
    const int rowq = blockIdx.x * 64 + wv * 16 + ((l >> 4) << 2);
    if (rowq < VOCAB) {
        float4 bd = *(const float4*)(bdec + rowq);
#pragma unroll
        for (int nt = 0; nt < 7; ++nt) {
            int tt = nt * 16 + (l & 15);
            if (tt <= 100) {
                float4 v;
                v.x = fmaxf(acc[nt][0] + bd.x, 0.f);
                v.y = fmaxf(acc[nt][1] + bd.y, 0.f);
                v.z = fmaxf(acc[nt][2] + bd.z, 0.f);
                v.w = fmaxf(acc[nt][3] + bd.w, 0.f);
                *(float4*)(out + (size_t)tt * VOCAB + rowq) = v;
            }
        }
    }
}

// ---------------- launch ----------------
extern "C" void kernel_launch(void* const* d_in, const int* in_sizes, int n_in,
                              void* d_out, int out_size, void* d_ws, size_t ws_size,
                              hipStream_t stream) {
    const float* board  = (const float*)d_in[0];
    const float* conv_w = (const float*)d_in[1];
    const float* conv_b = (const float*)d_in[2];
    const float* bn_g   = (const float*)d_in[3];
    const float* bn_b   = (const float*)d_in[4];
    const float* p      = (const float*)d_in[5];
    const float* Wlin   = (const float*)d_in[6];
    const float* blin   = (const float*)d_in[7];
    const float* Wih    = (const float*)d_in[8];
    const float* bih    = (const float*)d_in[9];
    const float* Whh    = (const float*)d_in[10];
    const float* bhh    = (const float*)d_in[11];
    const float* Wdec   = (const float*)d_in[12];
    const float* bdec   = (const float*)d_in[13];
    float* out = (float*)d_out;
    char* ws = (char*)d_ws;

    _Float16* wsum  = (_Float16*)(ws);             // 524288 B
    _Float16* Hg    = (_Float16*)(ws + 524288);    // 51712 B
    float* gates0   = (float*)(ws + 576000);       // 4096 B
    float* bsum     = (float*)(ws + 580096);       // 4096 B
    _Float16* wdh   = (_Float16*)(ws + 584192);    // 25600000 B
    const size_t NEED = 584192ull + 25600000ull;
    const bool fit = ws_size >= NEED;

    k_pre<<<10, 512, 0, stream>>>(board, conv_w, conv_b, bn_g, bn_b, p,
                                  Wlin, blin, Wih, bih, Whh, bhh,
                                  wsum, bsum, gates0);
    k_lstm<<<fit ? 129 : 1, 512, 132224, stream>>>(wsum, bsum, gates0, Hg, Wdec, wdh);
    if (fit)
        k_gemm_f16<<<782, 256, 0, stream>>>(wdh, bdec, Hg, out);
    else
        k_gemm_f32<<<782, 256, 0, stream>>>(Wdec, bdec, Hg, out);
}

// Round 3
// 513.957 us; speedup vs baseline: 1.0189x; 1.0189x over previous
//
#include <hip/hip_runtime.h>

typedef _Float16 v2h __attribute__((ext_vector_type(2)));
typedef _Float16 v8h __attribute__((ext_vector_type(8)));
typedef float v4f __attribute__((ext_vector_type(4)));

#define EMB 256
#define VOCAB 50000

// ---------------- helpers ----------------
__device__ __forceinline__ float sigf(float x) {
    return 1.f / (1.f + __expf(-x));
}
__device__ __forceinline__ float tanhf_(float x) {
    float e = __expf(2.f * fabsf(x));
    float th = 1.f - 2.f / (e + 1.f);
    return copysignf(th, x);
}
__device__ __forceinline__ float fdot2_(v2h a, v2h b, float c) {
    return __builtin_amdgcn_fdot2(a, b, c, false);
}

// ---------------- K1: conv/BN stack + feat + gates0 + wsum/bsum ----------------
// block 0: serial conv chain -> feat -> gates0 (one block, 512 thr)
// blocks 1..8: wsum = f16(Wih+Whh); block 9: bsum
__global__ __launch_bounds__(512) void k_pre(
        const float* __restrict__ board, const float* __restrict__ conv_w,
        const float* __restrict__ conv_b, const float* __restrict__ gamma,
        const float* __restrict__ beta, const float* __restrict__ p,
        const float* __restrict__ Wlin, const float* __restrict__ blin,
        const float* __restrict__ Wih, const float* __restrict__ bih,
        const float* __restrict__ Whh, const float* __restrict__ bhh,
        _Float16* __restrict__ wsum, float* __restrict__ bsum,
        float* __restrict__ gates0) {
    __shared__ float cur[361];
    __shared__ float feat_s[256];
    __shared__ float red1[8], red2[8], stats[2];
    const int b = blockIdx.x, t = threadIdx.x;
    if (b == 0) {
        const bool act = t < 361;
        const int r = t / 19, c = t % 19;
        float w[9];
#pragma unroll
        for (int k = 0; k < 9; ++k) w[k] = conv_w[k];
        const float cb = conv_b[0], ga = gamma[0], be = beta[0];
        float scales[8] = {p[0], p[1], p[2], p[3], p[4], p[5], p[6], 1.f};
        const int mode[8] = {2, 0, 1, 0, 1, 0, 1, 0};
        if (act) cur[t] = board[t];
        float d2r = 0.f;
        __syncthreads();
#pragma unroll
        for (int it = 0; it < 8; ++it) {
            float y = 0.f;
            if (act) {
#pragma unroll
                for (int di = 0; di < 3; ++di)
#pragma unroll
                    for (int dj = 0; dj < 3; ++dj) {
                        int rr = r + di - 1, cc2 = c + dj - 1;
                        if (rr >= 0 && rr < 19 && cc2 >= 0 && cc2 < 19)
                            y += cur[rr * 19 + cc2] * w[di * 3 + dj];
                    }
                y += cb;
            }
            float s1 = y, s2 = y * y;
            for (int m = 32; m; m >>= 1) {
                s1 += __shfl_xor(s1, m);
                s2 += __shfl_xor(s2, m);
            }
            const int wv = t >> 6;
            if ((t & 63) == 0) { red1[wv] = s1; red2[wv] = s2; }
            __syncthreads();
            if (t == 0) {
                float a = 0.f, b2 = 0.f;
                for (int i = 0; i < 8; ++i) { a += red1[i]; b2 += red2[i]; }
                float mu = a / 361.f;
                float var = b2 / 361.f - mu * mu;
                stats[0] = mu;
                stats[1] = rsqrtf(var + 1e-5f);
            }
            __syncthreads();
            float mu = stats[0], rs = stats[1];
            float v = ga * (y - mu) * rs + be;
            v *= scales[it];
            if (mode[it] == 1) v += d2r;
            v = fmaxf(v, 0.f);
            if (mode[it] != 0) d2r = v;
            if (act) cur[t] = v;
            __syncthreads();
        }
        // ---- feat = Wlin @ d1 + blin (row per 2 threads) ----
        {
            const int fr = t >> 1, fh = t & 1;
            const int k0 = fh ? 184 : 0, k1 = fh ? 361 : 184;
            const float* wrow = Wlin + fr * 361;
            float acc = 0.f;
            for (int k = k0; k < k1; ++k) acc += wrow[k] * cur[k];
            acc += __shfl_xor(acc, 1);
            if (fh == 0) feat_s[fr] = acc + blin[fr];
        }
        __syncthreads();
        // ---- gates0 = Wih @ feat + bih + bhh (2 rows per thread) ----
#pragma unroll
        for (int rr = 0; rr < 2; ++rr) {
            const int row = t + rr * 512;
            const float4* wr4 = (const float4*)(Wih + row * 256);
            float a = 0.f;
            for (int k = 0; k < 64; ++k) {
                float4 wv = wr4[k];
                float4 fv = *(const float4*)(feat_s + k * 4);
                a += wv.x * fv.x + wv.y * fv.y + wv.z * fv.z + wv.w * fv.w;
            }
            gates0[row] = a + bih[row] + bhh[row];
        }
    } else if (b <= 8) {
        const int base = (b - 1) * 32768 + t;
#pragma unroll
        for (int i = 0; i < 64; ++i) {
            int idx = base + i * 512;
            wsum[idx] = (_Float16)(Wih[idx] + Whh[idx]);
        }
    } else {
        for (int i = t; i < 1024; i += 512) bsum[i] = bih[i] + bhh[i];
    }
}

// ---------------- K2: 101-step LSTM chain (1 block x 512, weights resident) ----
// Thread t: g = t>>2 (cell group), ks = t&3 (k-slice of 64). Owns 8 gate rows:
// cells {g, g+128} x 4 gates, k in [ks*64, ks*64+64). First 48 k of each row in
// VGPRs (launch_bounds(512,1) -> 256-VGPR cap, need ~240), last 16 k in
// swizzled LDS. h double-buffered in LDS at 4 x 144 B slices (conflict-free).
__global__ __launch_bounds__(512, 1) void k_lstm(
        const _Float16* __restrict__ wsum, const float* __restrict__ bsum,
        const float* __restrict__ gates0, _Float16* __restrict__ Hg) {
    extern __shared__ char smem[];
    _Float16* Wl = (_Float16*)smem;          // 131072 B
    char* hb0 = smem + 131072;               // 2 x 576 B double buffer
    const int t = threadIdx.x;
    const int g = t >> 2;
    const int ks = t & 3;
    const int k0 = ks * 64;
    const int sw = (t & 15) << 4;

    int rows[8];
#pragma unroll
    for (int j = 0; j < 4; ++j) { rows[j] = g + 256 * j; rows[j + 4] = g + 128 + 256 * j; }

    // --- register-resident weights: 8 rows x 48 f16 = 192 VGPRs ---
    v2h wr[8][24];
#pragma unroll
    for (int j = 0; j < 8; ++j) {
        const _Float16* src = wsum + rows[j] * 256 + k0;
#pragma unroll
        for (int q6 = 0; q6 < 6; ++q6) {
            float4 fv = *(const float4*)(src + q6 * 8);
            const v2h* vp = (const v2h*)&fv;
            wr[j][q6 * 4 + 0] = vp[0];
            wr[j][q6 * 4 + 1] = vp[1];
            wr[j][q6 * 4 + 2] = vp[2];
            wr[j][q6 * 4 + 3] = vp[3];
        }
    }
    // pin in VGPRs: forbid rematerialization / re-load inside the loop
#pragma unroll
    for (int j = 0; j < 8; ++j)
#pragma unroll
        for (int q = 0; q < 24; ++q)
            asm volatile("" : "+v"(wr[j][q]));

    // --- LDS-resident weights: 8 rows x 16 f16, thread-major 256B, swizzled ---
#pragma unroll
    for (int j = 0; j < 8; ++j) {
        const _Float16* src = wsum + rows[j] * 256 + k0 + 48;
#pragma unroll
        for (int cc = 0; cc < 2; ++cc) {
            float4 fv = *(const float4*)(src + cc * 8);
            const int c = j * 2 + cc;
            *(float4*)((char*)Wl + t * 256 + ((c * 16) ^ sw)) = fv;
        }
    }
    float bsv[8];
#pragma unroll
    for (int j = 0; j < 8; ++j) bsv[j] = bsum[rows[j]];

    const int cell = (ks == 0) ? g : g + 128;            // valid for ks<2
    const int haddr = ((cell >> 6) * 144) + ((cell & 63) * 2);
    float cst = 0.f;
    // --- step 0 from precomputed gates0 ---
    if (ks < 2) {
        float gi = gates0[cell], gg = gates0[cell + 512], go = gates0[cell + 768];
        cst = sigf(gi) * tanhf_(gg);
        float h = sigf(go) * tanhf_(cst);
        *(_Float16*)(hb0 + haddr) = (_Float16)h;
        Hg[cell] = (_Float16)h;
    }
    __syncthreads();

    for (int step = 1; step <= 100; ++step) {
        const char* hr = hb0 + ((step + 1) & 1) * 576;
        char* hw = hb0 + (step & 1) * 576;
        const char* hsl = hr + ks * 144;
        float acc[8];
#pragma unroll
        for (int j = 0; j < 8; ++j) acc[j] = 0.f;
        // register-weight MACs: k in [k0, k0+48)
#pragma unroll
        for (int q = 0; q < 6; ++q) {
            float4 hv = *(const float4*)(hsl + q * 16);
            const v2h* h4 = (const v2h*)&hv;
#pragma unroll
            for (int j = 0; j < 8; ++j) {
#pragma unroll
                for (int u = 0; u < 4; ++u)
                    acc[j] = fdot2_(wr[j][q * 4 + u], h4[u], acc[j]);
            }
        }
        // LDS-weight MACs: k in [k0+48, k0+64)
#pragma unroll
        for (int cc = 0; cc < 2; ++cc) {
            float4 hv = *(const float4*)(hsl + 96 + cc * 16);
            const v2h* h4 = (const v2h*)&hv;
#pragma unroll
            for (int j = 0; j < 8; ++j) {
                const int c = j * 2 + cc;
                float4 wv = *(const float4*)((const char*)Wl + t * 256 + ((c * 16) ^ sw));
                const v2h* w4 = (const v2h*)&wv;
#pragma unroll
                for (int u = 0; u < 4; ++u)
                    acc[j] = fdot2_(w4[u], h4[u], acc[j]);
            }
        }
        // reduce across the 4 k-slices (same wave, lanes t^1, t^2)
#pragma unroll
        for (int j = 0; j < 8; ++j) {
            acc[j] += __shfl_xor(acc[j], 1);
            acc[j] += __shfl_xor(acc[j], 2);
        }
        if (ks < 2) {
            float gi, gf, gg, go;
            if (ks == 0) {
                gi = acc[0] + bsv[0]; gf = acc[1] + bsv[1];
                gg = acc[2] + bsv[2]; go = acc[3] + bsv[3];
            } else {
                gi = acc[4] + bsv[4]; gf = acc[5] + bsv[5];
                gg = acc[6] + bsv[6]; go = acc[7] + bsv[7];
            }
            cst = sigf(gf) * cst + sigf(gi) * tanhf_(gg);
            float h = sigf(go) * tanhf_(cst);
            *(_Float16*)(hw + haddr) = (_Float16)h;
            Hg[step * 256 + cell] = (_Float16)h;
        }
        __syncthreads();
    }
}

// ---------------- K3: logits GEMM [50048x256]x[256x112] via MFMA f16 ----------
// 512 threads / 8 waves per block, 128 A-rows per block, 391 blocks.
// LDS 59 KB -> 2 blocks/CU -> 16 waves/CU.
__global__ __launch_bounds__(512) void k_gemm(
        const float* __restrict__ Wdec, const float* __restrict__ bdec,
        const _Float16* __restrict__ Hg, float* __restrict__ out) {
    __shared__ _Float16 Hl[112 * 264];
    const int t = threadIdx.x;
    // zero the N-pad rows 101..111
    {
        float4 z; z.x = 0.f; z.y = 0.f; z.z = 0.f; z.w = 0.f;
        for (int i = t; i < 11 * 33; i += 512) {
            int row = 101 + i / 33, kc = i % 33;
            *(float4*)(Hl + row * 264 + kc * 8) = z;
        }
    }
    // stage H (101 rows x 256 f16)
    for (int i = t; i < 101 * 32; i += 512) {
        int row = i >> 5, kc = i & 31;
        float4 v = ((const float4*)Hg)[i];
        *(float4*)(Hl + row * 264 + kc * 8) = v;
    }
    __syncthreads();

    const int l = t & 63, wv = t >> 6;
    const int mrow = blockIdx.x * 128 + wv * 16 + (l & 15);
    const int mcl = (mrow < VOCAB) ? mrow : (VOCAB - 1);
    const float* arow = Wdec + (size_t)mcl * 256 + ((l >> 4) << 3);
    const _Float16* brow = Hl + (l & 15) * 264 + ((l >> 4) << 3);

    v4f acc[7];
#pragma unroll
    for (int nt = 0; nt < 7; ++nt) {
#pragma unroll
        for (int j = 0; j < 4; ++j) acc[nt][j] = 0.f;
    }
#pragma unroll
    for (int ks = 0; ks < 8; ++ks) {
        float4 a0 = *(const float4*)(arow + ks * 32);
        float4 a1 = *(const float4*)(arow + ks * 32 + 4);
        v8h af;
        af[0] = (_Float16)a0.x; af[1] = (_Float16)a0.y;
        af[2] = (_Float16)a0.z; af[3] = (_Float16)a0.w;
        af[4] = (_Float16)a1.x; af[5] = (_Float16)a1.y;
        af[6] = (_Float16)a1.z; af[7] = (_Float16)a1.w;
#pragma unroll
        for (int nt = 0; nt < 7; ++nt) {
            v8h bf = *(const v8h*)(brow + nt * 16 * 264 + ks * 32);
            acc[nt] = __builtin_amdgcn_mfma_f32_16x16x32_f16(af, bf, acc[nt], 0, 0, 0);
        }
    }
    const int rowq = blockIdx.x * 128 + wv * 16 + ((l >> 4) << 2);
    if (rowq < VOCAB) {
        float4 bd = *(const float4*)(bdec + rowq);
#pragma unroll
        for (int nt = 0; nt < 7; ++nt) {
            int tt = nt * 16 + (l & 15);
            if (tt <= 100) {
                float4 v;
                v.x = fmaxf(acc[nt][0] + bd.x, 0.f);
                v.y = fmaxf(acc[nt][1] + bd.y, 0.f);
                v.z = fmaxf(acc[nt][2] + bd.z, 0.f);
                v.w = fmaxf(acc[nt][3] + bd.w, 0.f);
                *(float4*)(out + (size_t)tt * VOCAB + rowq) = v;
            }
        }
    }
}

// ---------------- launch ----------------
extern "C" void kernel_launch(void* const* d_in, const int* in_sizes, int n_in,
                              void* d_out, int out_size, void* d_ws, size_t ws_size,
                              hipStream_t stream) {
    const float* board  = (const float*)d_in[0];
    const float* conv_w = (const float*)d_in[1];
    const float* conv_b = (const float*)d_in[2];
    const float* bn_g   = (const float*)d_in[3];
    const float* bn_b   = (const float*)d_in[4];
    const float* p      = (const float*)d_in[5];
    const float* Wlin   = (const float*)d_in[6];
    const float* blin   = (const float*)d_in[7];
    const float* Wih    = (const float*)d_in[8];
    const float* bih    = (const float*)d_in[9];
    const float* Whh    = (const float*)d_in[10];
    const float* bhh    = (const float*)d_in[11];
    const float* Wdec   = (const float*)d_in[12];
    const float* bdec   = (const float*)d_in[13];
    float* out = (float*)d_out;
    char* ws = (char*)d_ws;

    _Float16* wsum  = (_Float16*)(ws);             // 524288 B
    _Float16* Hg    = (_Float16*)(ws + 524288);    // 51712 B
    float* gates0   = (float*)(ws + 576000);       // 4096 B
    float* bsum     = (float*)(ws + 580096);       // 4096 B

    k_pre<<<10, 512, 0, stream>>>(board, conv_w, conv_b, bn_g, bn_b, p,
                                  Wlin, blin, Wih, bih, Whh, bhh,
                                  wsum, bsum, gates0);
    k_lstm<<<1, 512, 132224, stream>>>(wsum, bsum, gates0, Hg);
    k_gemm<<<391, 512, 0, stream>>>(Wdec, bdec, Hg, out);
}

// Round 4
// 492.442 us; speedup vs baseline: 1.0634x; 1.0437x over previous
//
#include <hip/hip_runtime.h>

typedef _Float16 v2h __attribute__((ext_vector_type(2)));
typedef _Float16 v8h __attribute__((ext_vector_type(8)));
typedef float v4f __attribute__((ext_vector_type(4)));

#define EMB 256
#define VOCAB 50000

// ---------------- helpers ----------------
__device__ __forceinline__ float sigf(float x) {
    return 1.f / (1.f + __expf(-x));
}
__device__ __forceinline__ float tanhf_(float x) {
    float e = __expf(2.f * fabsf(x));
    float th = 1.f - 2.f / (e + 1.f);
    return copysignf(th, x);
}
__device__ __forceinline__ float fdot2_(v2h a, v2h b, float c) {
    return __builtin_amdgcn_fdot2(a, b, c, false);
}

// ---------------- K1: conv/BN stack (1 block, 384 threads) ----------------
__global__ __launch_bounds__(384) void k_conv(
        const float* __restrict__ board, const float* __restrict__ conv_w,
        const float* __restrict__ conv_b, const float* __restrict__ gamma,
        const float* __restrict__ beta, const float* __restrict__ p,
        float* __restrict__ d1_out) {
    __shared__ float cur[361];
    __shared__ float red1[8], red2[8];
    __shared__ float stats[2];
    const int t = threadIdx.x;
    const bool act = t < 361;
    const int r = t / 19, c = t % 19;
    float w[9];
#pragma unroll
    for (int k = 0; k < 9; ++k) w[k] = conv_w[k];
    const float cb = conv_b[0], ga = gamma[0], be = beta[0];
    float scales[8] = {p[0], p[1], p[2], p[3], p[4], p[5], p[6], 1.f};
    const int mode[8] = {2, 0, 1, 0, 1, 0, 1, 0};
    if (act) cur[t] = board[t];
    float d2r = 0.f;
    __syncthreads();
#pragma unroll
    for (int it = 0; it < 8; ++it) {
        float y = 0.f;
        if (act) {
#pragma unroll
            for (int di = 0; di < 3; ++di)
#pragma unroll
                for (int dj = 0; dj < 3; ++dj) {
                    int rr = r + di - 1, cc2 = c + dj - 1;
                    if (rr >= 0 && rr < 19 && cc2 >= 0 && cc2 < 19)
                        y += cur[rr * 19 + cc2] * w[di * 3 + dj];
                }
            y += cb;
        }
        float s1 = y, s2 = y * y;
        for (int m = 32; m; m >>= 1) {
            s1 += __shfl_xor(s1, m);
            s2 += __shfl_xor(s2, m);
        }
        const int wv = t >> 6;
        if ((t & 63) == 0) { red1[wv] = s1; red2[wv] = s2; }
        __syncthreads();
        if (t == 0) {
            float a = 0.f, b2 = 0.f;
            for (int i = 0; i < 6; ++i) { a += red1[i]; b2 += red2[i]; }
            float mu = a / 361.f;
            float var = b2 / 361.f - mu * mu;
            stats[0] = mu;
            stats[1] = rsqrtf(var + 1e-5f);
        }
        __syncthreads();
        float mu = stats[0], rs = stats[1];
        float v = ga * (y - mu) * rs + be;
        v *= scales[it];
        if (mode[it] == 1) v += d2r;
        v = fmaxf(v, 0.f);
        if (mode[it] != 0) d2r = v;
        if (act) cur[t] = v;
        __syncthreads();
    }
    if (act) d1_out[t] = cur[t];
}

// ---------------- K2: feat + W_sum(f16) + b_sum (81 blocks x 256) ----------------
__global__ __launch_bounds__(256) void k_prep(
        const float* __restrict__ Wlin, const float* __restrict__ blin,
        const float* __restrict__ d1,
        const float* __restrict__ Wih, const float* __restrict__ bih,
        const float* __restrict__ Whh, const float* __restrict__ bhh,
        float* __restrict__ feat, _Float16* __restrict__ wsum,
        float* __restrict__ bsum) {
    const int b = blockIdx.x, t = threadIdx.x;
    if (b < 16) {
        const int r = b * 16 + (t >> 4), kc = t & 15;
        const int k0 = kc * 23, k1 = (k0 + 23 < 361) ? k0 + 23 : 361;
        const float* wrow = Wlin + r * 361;
        float acc = 0.f;
        for (int k = k0; k < k1; ++k) acc += wrow[k] * d1[k];
        for (int m = 1; m < 16; m <<= 1) acc += __shfl_xor(acc, m);
        if (kc == 0) feat[r] = acc + blin[r];
    } else if (b < 80) {
        const int base = (b - 16) * 4096 + t;
#pragma unroll
        for (int i = 0; i < 16; ++i) {
            int idx = base + i * 256;
            wsum[idx] = (_Float16)(Wih[idx] + Whh[idx]);
        }
    } else {
        for (int i = t; i < 1024; i += 256) bsum[i] = bih[i] + bhh[i];
    }
}

// ---------------- K2b: gates0 = W_ih@feat + b_ih + b_hh (64 blocks x 256) -------
__global__ __launch_bounds__(256) void k_gates0(
        const float* __restrict__ Wih, const float* __restrict__ feat,
        const float* __restrict__ bih, const float* __restrict__ bhh,
        float* __restrict__ gates0) {
    const int r = blockIdx.x * 16 + (threadIdx.x >> 4), kc = threadIdx.x & 15;
    const float* wrow = Wih + r * 256 + kc * 16;
    const float* f = feat + kc * 16;
    float acc = 0.f;
#pragma unroll
    for (int k = 0; k < 16; ++k) acc += wrow[k] * f[k];
    for (int m = 1; m < 16; m <<= 1) acc += __shfl_xor(acc, m);
    if (kc == 0) gates0[r] = acc + bih[r] + bhh[r];
}

// ---------------- K3: 101-step LSTM chain (1 block x 256, weights resident) ----
// Thread t: g = t>>2 (0..63), ks = t&3 (k-slice of 64). Owns 16 gate rows:
// cells {g, g+64, g+128, g+192} x 4 gates, k in [ks*64, ks*64+64).
// First 48 k of each row in VGPRs (16x24 v2h = 384 regs; cap 512 at 4 waves =
// 1 wave/SIMD via launch_bounds(256,1)). Last 16 k of each row in swizzled LDS
// (512 B/thread = 128 KiB). h double-buffered in LDS (2 x 512 B).
__global__ __launch_bounds__(256, 1) void k_lstm(
        const _Float16* __restrict__ wsum, const float* __restrict__ bsum,
        const float* __restrict__ gates0, _Float16* __restrict__ Hg) {
    extern __shared__ char smem[];
    _Float16* Wl = (_Float16*)smem;          // 131072 B
    char* hb0 = smem + 131072;               // 2 x 512 B double buffer
    const int t = threadIdx.x;
    const int g = t >> 2;
    const int ks = t & 3;
    const int k0 = ks * 64;
    const int sw = (t & 15) << 4;

    // --- register-resident weights: 16 rows x 48 f16 = 384 VGPRs ---
    v2h wr[16][24];
#pragma unroll
    for (int m = 0; m < 4; ++m) {
#pragma unroll
        for (int j = 0; j < 4; ++j) {
            const int row = (g + 64 * m) + 256 * j;
            const _Float16* src = wsum + row * 256 + k0;
            const int rr = m * 4 + j;
#pragma unroll
            for (int q6 = 0; q6 < 6; ++q6) {
                float4 fv = *(const float4*)(src + q6 * 8);
                const v2h* vp = (const v2h*)&fv;
                wr[rr][q6 * 4 + 0] = vp[0];
                wr[rr][q6 * 4 + 1] = vp[1];
                wr[rr][q6 * 4 + 2] = vp[2];
                wr[rr][q6 * 4 + 3] = vp[3];
            }
        }
    }
    // pin in VGPRs (forbid rematerialization)
#pragma unroll
    for (int rr = 0; rr < 16; ++rr)
#pragma unroll
        for (int q = 0; q < 24; ++q)
            asm("" : "+v"(wr[rr][q]));

    // --- LDS-resident weights: 16 rows x 16 f16 = 512 B/thread, swizzled ---
#pragma unroll
    for (int m = 0; m < 4; ++m) {
#pragma unroll
        for (int j = 0; j < 4; ++j) {
            const int row = (g + 64 * m) + 256 * j;
            const _Float16* src = wsum + row * 256 + k0 + 48;
            const int rr = m * 4 + j;
#pragma unroll
            for (int cc = 0; cc < 2; ++cc) {
                float4 fv = *(const float4*)(src + cc * 8);
                const int c = rr * 2 + cc;
                *(float4*)((char*)Wl + t * 512 + ((c * 16) ^ sw)) = fv;
            }
        }
    }
    float bsv[4];
    const int cellT = g + 64 * ks;
#pragma unroll
    for (int j = 0; j < 4; ++j) bsv[j] = bsum[cellT + 256 * j];

    float cst = 0.f;
    // --- step 0 from precomputed gates0 (c = 0 so f-gate drops out) ---
    {
        float gi = gates0[cellT], gg = gates0[cellT + 512], go = gates0[cellT + 768];
        cst = sigf(gi) * tanhf_(gg);
        float h = sigf(go) * tanhf_(cst);
        *(_Float16*)(hb0 + cellT * 2) = (_Float16)h;
        Hg[cellT] = (_Float16)h;
    }
    __syncthreads();

    for (int step = 1; step <= 100; ++step) {
        const char* hr = hb0 + ((step + 1) & 1) * 512;
        char* hw = hb0 + (step & 1) * 512;
        const char* hsl = hr + ks * 128;
        float acc[16];
#pragma unroll
        for (int rr = 0; rr < 16; ++rr) acc[rr] = 0.f;
        // register-weight MACs: k in [k0, k0+48)
#pragma unroll
        for (int q = 0; q < 6; ++q) {
            float4 hv = *(const float4*)(hsl + q * 16);
            const v2h* h4 = (const v2h*)&hv;
#pragma unroll
            for (int rr = 0; rr < 16; ++rr) {
#pragma unroll
                for (int u = 0; u < 4; ++u)
                    acc[rr] = fdot2_(wr[rr][q * 4 + u], h4[u], acc[rr]);
            }
        }
        // LDS-weight MACs: k in [k0+48, k0+64)
#pragma unroll
        for (int cc = 0; cc < 2; ++cc) {
            float4 hv = *(const float4*)(hsl + 96 + cc * 16);
            const v2h* h4 = (const v2h*)&hv;
#pragma unroll
            for (int rr = 0; rr < 16; ++rr) {
                const int c = rr * 2 + cc;
                float4 wv = *(const float4*)((const char*)Wl + t * 512 + ((c * 16) ^ sw));
                const v2h* w4 = (const v2h*)&wv;
#pragma unroll
                for (int u = 0; u < 4; ++u)
                    acc[rr] = fdot2_(w4[u], h4[u], acc[rr]);
            }
        }
        // reduce across the 4 k-slices (lanes t^1, t^2 within quad)
#pragma unroll
        for (int rr = 0; rr < 16; ++rr) {
            acc[rr] += __shfl_xor(acc[rr], 1);
            acc[rr] += __shfl_xor(acc[rr], 2);
        }
        // thread (g,ks) finalizes cell g + 64*ks  (m == ks block of acc)
        float gi = ks == 0 ? acc[0] : ks == 1 ? acc[4] : ks == 2 ? acc[8]  : acc[12];
        float gf = ks == 0 ? acc[1] : ks == 1 ? acc[5] : ks == 2 ? acc[9]  : acc[13];
        float gg = ks == 0 ? acc[2] : ks == 1 ? acc[6] : ks == 2 ? acc[10] : acc[14];
        float go = ks == 0 ? acc[3] : ks == 1 ? acc[7] : ks == 2 ? acc[11] : acc[15];
        gi += bsv[0]; gf += bsv[1]; gg += bsv[2]; go += bsv[3];
        cst = sigf(gf) * cst + sigf(gi) * tanhf_(gg);
        float h = sigf(go) * tanhf_(cst);
        *(_Float16*)(hw + cellT * 2) = (_Float16)h;
        Hg[step * 256 + cellT] = (_Float16)h;
        __syncthreads();
    }
}

// ---------------- K4: logits GEMM [50048x256]x[256x112] via MFMA f16 ----------
__global__ __launch_bounds__(256) void k_gemm(
        const float* __restrict__ Wdec, const float* __restrict__ bdec,
        const _Float16* __restrict__ Hg, float* __restrict__ out) {
    __shared__ _Float16 Hl[112 * 264];
    const int t = threadIdx.x;
    float4 z; z.x = 0.f; z.y = 0.f; z.z = 0.f; z.w = 0.f;
    for (int i = t; i < 3696; i += 256) ((float4*)Hl)[i] = z;
    __syncthreads();
    for (int i = t; i < 101 * 32; i += 256) {
        int row = i >> 5, kc = i & 31;
        float4 v = ((const float4*)Hg)[i];
        *(float4*)(Hl + row * 264 + kc * 8) = v;
    }
    __syncthreads();

    const int l = t & 63, wv = t >> 6;
    const int mrow = blockIdx.x * 64 + wv * 16 + (l & 15);
    const int mcl = (mrow < VOCAB) ? mrow : (VOCAB - 1);
    const float* arow = Wdec + (size_t)mcl * 256 + ((l >> 4) << 3);
    const _Float16* brow = Hl + (l & 15) * 264 + ((l >> 4) << 3);

    v4f acc[7];
#pragma unroll
    for (int nt = 0; nt < 7; ++nt) {
#pragma unroll
        for (int j = 0; j < 4; ++j) acc[nt][j] = 0.f;
    }
#pragma unroll
    for (int ks = 0; ks < 8; ++ks) {
        float4 a0 = *(const float4*)(arow + ks * 32);
        float4 a1 = *(const float4*)(arow + ks * 32 + 4);
        v8h af;
        af[0] = (_Float16)a0.x; af[1] = (_Float16)a0.y;
        af[2] = (_Float16)a0.z; af[3] = (_Float16)a0.w;
        af[4] = (_Float16)a1.x; af[5] = (_Float16)a1.y;
        af[6] = (_Float16)a1.z; af[7] = (_Float16)a1.w;
#pragma unroll
        for (int nt = 0; nt < 7; ++nt) {
            v8h bf = *(const v8h*)(brow + nt * 16 * 264 + ks * 32);
            acc[nt] = __builtin_amdgcn_mfma_f32_16x16x32_f16(af, bf, acc[nt], 0, 0, 0);
        }
    }
    const int rowq = blockIdx.x * 64 + wv * 16 + ((l >> 4) << 2);
    if (rowq < VOCAB) {
        float4 bd = *(const float4*)(bdec + rowq);
#pragma unroll
        for (int nt = 0; nt < 7; ++nt) {
            int tt = nt * 16 + (l & 15);
            if (tt <= 100) {
                float4 v;
                v.x = fmaxf(acc[nt][0] + bd.x, 0.f);
                v.y = fmaxf(acc[nt][1] + bd.y, 0.f);
                v.z = fmaxf(acc[nt][2] + bd.z, 0.f);
                v.w = fmaxf(acc[nt][3] + bd.w, 0.f);
                *(float4*)(out + (size_t)tt * VOCAB + rowq) = v;
            }
        }
    }
}

// ---------------- launch ----------------
extern "C" void kernel_launch(void* const* d_in, const int* in_sizes, int n_in,
                              void* d_out, int out_size, void* d_ws, size_t ws_size,
                              hipStream_t stream) {
    const float* board  = (const float*)d_in[0];
    const float* conv_w = (const float*)d_in[1];
    const float* conv_b = (const float*)d_in[2];
    const float* bn_g   = (const float*)d_in[3];
    const float* bn_b   = (const float*)d_in[4];
    const float* p      = (const float*)d_in[5];
    const float* Wlin   = (const float*)d_in[6];
    const float* blin   = (const float*)d_in[7];
    const float* Wih    = (const float*)d_in[8];
    const float* bih    = (const float*)d_in[9];
    const float* Whh    = (const float*)d_in[10];
    const float* bhh    = (const float*)d_in[11];
    const float* Wdec   = (const float*)d_in[12];
    const float* bdec   = (const float*)d_in[13];
    float* out = (float*)d_out;
    char* ws = (char*)d_ws;

    _Float16* wsum  = (_Float16*)(ws);             // 524288 B
    _Float16* Hg    = (_Float16*)(ws + 524288);    // 51712 B
    float* d1       = (float*)(ws + 576512);       // 1444 B
    float* feat     = (float*)(ws + 578560);       // 1024 B
    float* gates0   = (float*)(ws + 579584);       // 4096 B
    float* bsum     = (float*)(ws + 583680);       // 4096 B

    k_conv<<<1, 384, 0, stream>>>(board, conv_w, conv_b, bn_g, bn_b, p, d1);
    k_prep<<<81, 256, 0, stream>>>(Wlin, blin, d1, Wih, bih, Whh, bhh, feat, wsum, bsum);
    k_gates0<<<64, 256, 0, stream>>>(Wih, feat, bih, bhh, gates0);
    k_lstm<<<1, 256, 132096, stream>>>(wsum, bsum, gates0, Hg);
    k_gemm<<<782, 256, 0, stream>>>(Wdec, bdec, Hg, out);
}

// Round 5
// 384.920 us; speedup vs baseline: 1.3605x; 1.2793x over previous
//
#include <hip/hip_runtime.h>

typedef _Float16 v2h __attribute__((ext_vector_type(2)));
typedef _Float16 v8h __attribute__((ext_vector_type(8)));
typedef float v4f __attribute__((ext_vector_type(4)));

#define EMB 256
#define VOCAB 50000

// ---------------- helpers ----------------
__device__ __forceinline__ float sigf(float x) {
    return 1.f / (1.f + __expf(-x));
}
__device__ __forceinline__ float tanhf_(float x) {
    float e = __expf(2.f * fabsf(x));
    float th = 1.f - 2.f / (e + 1.f);
    return copysignf(th, x);
}
__device__ __forceinline__ float fdot2_(v2h a, v2h b, float c) {
    return __builtin_amdgcn_fdot2(a, b, c, false);
}

// ---------------- K1: conv/BN stack (1 block, 384 threads) ----------------
__global__ __launch_bounds__(384) void k_conv(
        const float* __restrict__ board, const float* __restrict__ conv_w,
        const float* __restrict__ conv_b, const float* __restrict__ gamma,
        const float* __restrict__ beta, const float* __restrict__ p,
        float* __restrict__ d1_out) {
    __shared__ float cur[361];
    __shared__ float red1[8], red2[8];
    __shared__ float stats[2];
    const int t = threadIdx.x;
    const bool act = t < 361;
    const int r = t / 19, c = t % 19;
    float w[9];
#pragma unroll
    for (int k = 0; k < 9; ++k) w[k] = conv_w[k];
    const float cb = conv_b[0], ga = gamma[0], be = beta[0];
    float scales[8] = {p[0], p[1], p[2], p[3], p[4], p[5], p[6], 1.f};
    const int mode[8] = {2, 0, 1, 0, 1, 0, 1, 0};
    if (act) cur[t] = board[t];
    float d2r = 0.f;
    __syncthreads();
#pragma unroll
    for (int it = 0; it < 8; ++it) {
        float y = 0.f;
        if (act) {
#pragma unroll
            for (int di = 0; di < 3; ++di)
#pragma unroll
                for (int dj = 0; dj < 3; ++dj) {
                    int rr = r + di - 1, cc2 = c + dj - 1;
                    if (rr >= 0 && rr < 19 && cc2 >= 0 && cc2 < 19)
                        y += cur[rr * 19 + cc2] * w[di * 3 + dj];
                }
            y += cb;
        }
        float s1 = y, s2 = y * y;
        for (int m = 32; m; m >>= 1) {
            s1 += __shfl_xor(s1, m);
            s2 += __shfl_xor(s2, m);
        }
        const int wv = t >> 6;
        if ((t & 63) == 0) { red1[wv] = s1; red2[wv] = s2; }
        __syncthreads();
        if (t == 0) {
            float a = 0.f, b2 = 0.f;
            for (int i = 0; i < 6; ++i) { a += red1[i]; b2 += red2[i]; }
            float mu = a / 361.f;
            float var = b2 / 361.f - mu * mu;
            stats[0] = mu;
            stats[1] = rsqrtf(var + 1e-5f);
        }
        __syncthreads();
        float mu = stats[0], rs = stats[1];
        float v = ga * (y - mu) * rs + be;
        v *= scales[it];
        if (mode[it] == 1) v += d2r;
        v = fmaxf(v, 0.f);
        if (mode[it] != 0) d2r = v;
        if (act) cur[t] = v;
        __syncthreads();
    }
    if (act) d1_out[t] = cur[t];
}

// ---------------- K2: feat + W_sum(f16) + b_sum (81 blocks x 256) ----------------
__global__ __launch_bounds__(256) void k_prep(
        const float* __restrict__ Wlin, const float* __restrict__ blin,
        const float* __restrict__ d1,
        const float* __restrict__ Wih, const float* __restrict__ bih,
        const float* __restrict__ Whh, const float* __restrict__ bhh,
        float* __restrict__ feat, _Float16* __restrict__ wsum,
        float* __restrict__ bsum) {
    const int b = blockIdx.x, t = threadIdx.x;
    if (b < 16) {
        const int r = b * 16 + (t >> 4), kc = t & 15;
        const int k0 = kc * 23, k1 = (k0 + 23 < 361) ? k0 + 23 : 361;
        const float* wrow = Wlin + r * 361;
        float acc = 0.f;
        for (int k = k0; k < k1; ++k) acc += wrow[k] * d1[k];
        for (int m = 1; m < 16; m <<= 1) acc += __shfl_xor(acc, m);
        if (kc == 0) feat[r] = acc + blin[r];
    } else if (b < 80) {
        const int base = (b - 16) * 4096 + t;
#pragma unroll
        for (int i = 0; i < 16; ++i) {
            int idx = base + i * 256;
            wsum[idx] = (_Float16)(Wih[idx] + Whh[idx]);
        }
    } else {
        for (int i = t; i < 1024; i += 256) bsum[i] = bih[i] + bhh[i];
    }
}

// ---------------- K2b: gates0 = W_ih@feat + b_ih + b_hh (64 blocks x 256) -------
__global__ __launch_bounds__(256) void k_gates0(
        const float* __restrict__ Wih, const float* __restrict__ feat,
        const float* __restrict__ bih, const float* __restrict__ bhh,
        float* __restrict__ gates0) {
    const int r = blockIdx.x * 16 + (threadIdx.x >> 4), kc = threadIdx.x & 15;
    const float* wrow = Wih + r * 256 + kc * 16;
    const float* f = feat + kc * 16;
    float acc = 0.f;
#pragma unroll
    for (int k = 0; k < 16; ++k) acc += wrow[k] * f[k];
    for (int m = 1; m < 16; m <<= 1) acc += __shfl_xor(acc, m);
    if (kc == 0) gates0[r] = acc + bih[r] + bhh[r];
}

// ---------------- K3: 101-step LSTM chain (1 block x 256) --------------------
// Thread t: g = t>>2 (0..63), ks = t&3 (k-slice of 64). Owns 16 gate rows
// (cells {g, g+64, g+128, g+192} x 4 gates), k in [ks*64, ks*64+64).
// Weight residency (512 KB total == whole CU unified register file + LDS):
//   k[0,48) rows 0..6  -> arch VGPRs   (7 x 24 v2h = 168 regs)
//   k[0,48) rows 7..15 -> AGPRs        (9 x 24 v2h = 216 regs, "+a" pinned)
//   k[48,64) all rows  -> swizzled LDS (16 x 8 v2h = 512 B/thread = 128 KiB)
// h double-buffered in LDS (2 x 512 B). WG=256 => 1 wave/SIMD => 512 unified
// regs/thread available (256 VGPR + 256 AGPR).
__global__ __launch_bounds__(256, 1) void k_lstm(
        const _Float16* __restrict__ wsum, const float* __restrict__ bsum,
        const float* __restrict__ gates0, _Float16* __restrict__ Hg) {
    extern __shared__ char smem[];
    _Float16* Wl = (_Float16*)smem;          // 131072 B
    char* hb0 = smem + 131072;               // 2 x 512 B double buffer
    const int t = threadIdx.x;
    const int g = t >> 2;
    const int ks = t & 3;
    const int k0 = ks * 64;
    const int sw = (t & 15) << 4;

    // --- load register-resident weights: rows 0..6 -> VGPR, 7..15 -> AGPR ---
    v2h wv[7][24];
    v2h wa[9][24];
#pragma unroll
    for (int m = 0; m < 4; ++m) {
#pragma unroll
        for (int j = 0; j < 4; ++j) {
            const int rr = m * 4 + j;
            const int row = (g + 64 * m) + 256 * j;
            const _Float16* src = wsum + row * 256 + k0;
#pragma unroll
            for (int q6 = 0; q6 < 6; ++q6) {
                float4 fv = *(const float4*)(src + q6 * 8);
                const v2h* vp = (const v2h*)&fv;
#pragma unroll
                for (int u = 0; u < 4; ++u) {
                    if (rr < 7) wv[rr][q6 * 4 + u] = vp[u];
                    else        wa[rr - 7][q6 * 4 + u] = vp[u];
                }
            }
        }
    }
    // pin: rows 0..6 in arch VGPRs, rows 7..15 in AGPRs
#pragma unroll
    for (int rr = 0; rr < 7; ++rr)
#pragma unroll
        for (int q = 0; q < 24; ++q)
            asm("" : "+v"(wv[rr][q]));
#pragma unroll
    for (int rr = 0; rr < 9; ++rr)
#pragma unroll
        for (int q = 0; q < 24; ++q)
            asm("" : "+a"(wa[rr][q]));

    // --- LDS-resident weights: 16 rows x 8 v2h (k[48,64)), swizzled ---
#pragma unroll
    for (int m = 0; m < 4; ++m) {
#pragma unroll
        for (int j = 0; j < 4; ++j) {
            const int rr = m * 4 + j;
            const int row = (g + 64 * m) + 256 * j;
            const _Float16* src = wsum + row * 256 + k0 + 48;
#pragma unroll
            for (int cc = 0; cc < 2; ++cc) {
                float4 fv = *(const float4*)(src + cc * 8);
                const int c = rr * 2 + cc;
                *(float4*)((char*)Wl + t * 512 + ((c * 16) ^ sw)) = fv;
            }
        }
    }
    float bsv[4];
    const int cellT = g + 64 * ks;
#pragma unroll
    for (int j = 0; j < 4; ++j) bsv[j] = bsum[cellT + 256 * j];

    float cst = 0.f;
    // --- step 0 from precomputed gates0 (c = 0 so f-gate drops out) ---
    {
        float gi = gates0[cellT], gg = gates0[cellT + 512], go = gates0[cellT + 768];
        cst = sigf(gi) * tanhf_(gg);
        float h = sigf(go) * tanhf_(cst);
        *(_Float16*)(hb0 + cellT * 2) = (_Float16)h;
        Hg[cellT] = (_Float16)h;
    }
    __syncthreads();

    for (int step = 1; step <= 100; ++step) {
        // keep residency pinned across iterations
#pragma unroll
        for (int rr = 0; rr < 7; ++rr)
#pragma unroll
            for (int q = 0; q < 24; ++q)
                asm("" : "+v"(wv[rr][q]));
#pragma unroll
        for (int rr = 0; rr < 9; ++rr)
#pragma unroll
            for (int q = 0; q < 24; ++q)
                asm("" : "+a"(wa[rr][q]));

        const char* hr = hb0 + ((step + 1) & 1) * 512;
        char* hw = hb0 + (step & 1) * 512;
        const char* hsl = hr + ks * 128;
        float acc[16];
#pragma unroll
        for (int rr = 0; rr < 16; ++rr) acc[rr] = 0.f;
        // register-weight MACs: k in [k0, k0+48)
#pragma unroll
        for (int q = 0; q < 6; ++q) {
            float4 hv = *(const float4*)(hsl + q * 16);
            const v2h* h4 = (const v2h*)&hv;
#pragma unroll
            for (int rr = 0; rr < 16; ++rr) {
#pragma unroll
                for (int u = 0; u < 4; ++u) {
                    v2h wq;
                    if (rr < 7) wq = wv[rr][q * 4 + u];
                    else        wq = wa[rr - 7][q * 4 + u];
                    acc[rr] = fdot2_(wq, h4[u], acc[rr]);
                }
            }
        }
        // LDS-weight MACs: k in [k0+48, k0+64)
#pragma unroll
        for (int cc = 0; cc < 2; ++cc) {
            float4 hv = *(const float4*)(hsl + 96 + cc * 16);
            const v2h* h4 = (const v2h*)&hv;
#pragma unroll
            for (int rr = 0; rr < 16; ++rr) {
                const int c = rr * 2 + cc;
                float4 wvv = *(const float4*)((const char*)Wl + t * 512 + ((c * 16) ^ sw));
                const v2h* w4 = (const v2h*)&wvv;
#pragma unroll
                for (int u = 0; u < 4; ++u)
                    acc[rr] = fdot2_(w4[u], h4[u], acc[rr]);
            }
        }
        // reduce across the 4 k-slices (lanes t^1, t^2 within quad)
#pragma unroll
        for (int rr = 0; rr < 16; ++rr) {
            acc[rr] += __shfl_xor(acc[rr], 1);
            acc[rr] += __shfl_xor(acc[rr], 2);
        }
        // thread (g,ks) finalizes cell g + 64*ks (acc block m == ks)
        float gi = ks == 0 ? acc[0] : ks == 1 ? acc[4] : ks == 2 ? acc[8]  : acc[12];
        float gf = ks == 0 ? acc[1] : ks == 1 ? acc[5] : ks == 2 ? acc[9]  : acc[13];
        float gg = ks == 0 ? acc[2] : ks == 1 ? acc[6] : ks == 2 ? acc[10] : acc[14];
        float go = ks == 0 ? acc[3] : ks == 1 ? acc[7] : ks == 2 ? acc[11] : acc[15];
        gi += bsv[0]; gf += bsv[1]; gg += bsv[2]; go += bsv[3];
        cst = sigf(gf) * cst + sigf(gi) * tanhf_(gg);
        float h = sigf(go) * tanhf_(cst);
        *(_Float16*)(hw + cellT * 2) = (_Float16)h;
        Hg[step * 256 + cellT] = (_Float16)h;
        __syncthreads();
    }
}

// ---------------- K4: logits GEMM [50048x256]x[256x112] via MFMA f16 ----------
__global__ __launch_bounds__(256) void k_gemm(
        const float* __restrict__ Wdec, const float* __restrict__ bdec,
        const _Float16* __restrict__ Hg, float* __restrict__ out) {
    __shared__ _Float16 Hl[112 * 264];
    const int t = threadIdx.x;
    float4 z; z.x = 0.f; z.y = 0.f; z.z = 0.f; z.w = 0.f;
    for (int i = t; i < 3696; i += 256) ((float4*)Hl)[i] = z;
    __syncthreads();
    for (int i = t; i < 101 * 32; i += 256) {
        int row = i >> 5, kc = i & 31;
        float4 v = ((const float4*)Hg)[i];
        *(float4*)(Hl + row * 264 + kc * 8) = v;
    }
    __syncthreads();

    const int l = t & 63, wv = t >> 6;
    const int mrow = blockIdx.x * 64 + wv * 16 + (l & 15);
    const int mcl = (mrow < VOCAB) ? mrow : (VOCAB - 1);
    const float* arow = Wdec + (size_t)mcl * 256 + ((l >> 4) << 3);
    const _Float16* brow = Hl + (l & 15) * 264 + ((l >> 4) << 3);

    v4f acc[7];
#pragma unroll
    for (int nt = 0; nt < 7; ++nt) {
#pragma unroll
        for (int j = 0; j < 4; ++j) acc[nt][j] = 0.f;
    }
#pragma unroll
    for (int ks = 0; ks < 8; ++ks) {
        float4 a0 = *(const float4*)(arow + ks * 32);
        float4 a1 = *(const float4*)(arow + ks * 32 + 4);
        v8h af;
        af[0] = (_Float16)a0.x; af[1] = (_Float16)a0.y;
        af[2] = (_Float16)a0.z; af[3] = (_Float16)a0.w;
        af[4] = (_Float16)a1.x; af[5] = (_Float16)a1.y;
        af[6] = (_Float16)a1.z; af[7] = (_Float16)a1.w;
#pragma unroll
        for (int nt = 0; nt < 7; ++nt) {
            v8h bf = *(const v8h*)(brow + nt * 16 * 264 + ks * 32);
            acc[nt] = __builtin_amdgcn_mfma_f32_16x16x32_f16(af, bf, acc[nt], 0, 0, 0);
        }
    }
    const int rowq = blockIdx.x * 64 + wv * 16 + ((l >> 4) << 2);
    if (rowq < VOCAB) {
        float4 bd = *(const float4*)(bdec + rowq);
#pragma unroll
        for (int nt = 0; nt < 7; ++nt) {
            int tt = nt * 16 + (l & 15);
            if (tt <= 100) {
                float4 v;
                v.x = fmaxf(acc[nt][0] + bd.x, 0.f);
                v.y = fmaxf(acc[nt][1] + bd.y, 0.f);
                v.z = fmaxf(acc[nt][2] + bd.z, 0.f);
                v.w = fmaxf(acc[nt][3] + bd.w, 0.f);
                *(float4*)(out + (size_t)tt * VOCAB + rowq) = v;
            }
        }
    }
}

// ---------------- launch ----------------
extern "C" void kernel_launch(void* const* d_in, const int* in_sizes, int n_in,
                              void* d_out, int out_size, void* d_ws, size_t ws_size,
                              hipStream_t stream) {
    const float* board  = (const float*)d_in[0];
    const float* conv_w = (const float*)d_in[1];
    const float* conv_b = (const float*)d_in[2];
    const float* bn_g   = (const float*)d_in[3];
    const float* bn_b   = (const float*)d_in[4];
    const float* p      = (const float*)d_in[5];
    const float* Wlin   = (const float*)d_in[6];
    const float* blin   = (const float*)d_in[7];
    const float* Wih    = (const float*)d_in[8];
    const float* bih    = (const float*)d_in[9];
    const float* Whh    = (const float*)d_in[10];
    const float* bhh    = (const float*)d_in[11];
    const float* Wdec   = (const float*)d_in[12];
    const float* bdec   = (const float*)d_in[13];
    float* out = (float*)d_out;
    char* ws = (char*)d_ws;

    _Float16* wsum  = (_Float16*)(ws);             // 524288 B
    _Float16* Hg    = (_Float16*)(ws + 524288);    // 51712 B
    float* d1       = (float*)(ws + 576512);       // 1444 B
    float* feat     = (float*)(ws + 578560);       // 1024 B
    float* gates0   = (float*)(ws + 579584);       // 4096 B
    float* bsum     = (float*)(ws + 583680);       // 4096 B

    k_conv<<<1, 384, 0, stream>>>(board, conv_w, conv_b, bn_g, bn_b, p, d1);
    k_prep<<<81, 256, 0, stream>>>(Wlin, blin, d1, Wih, bih, Whh, bhh, feat, wsum, bsum);
    k_gates0<<<64, 256, 0, stream>>>(Wih, feat, bih, bhh, gates0);
    k_lstm<<<1, 256, 132096, stream>>>(wsum, bsum, gates0, Hg);
    k_gemm<<<782, 256, 0, stream>>>(Wdec, bdec, Hg, out);
}

// Round 6
// 337.969 us; speedup vs baseline: 1.5495x; 1.1389x over previous
//
#include <hip/hip_runtime.h>

typedef _Float16 v2h __attribute__((ext_vector_type(2)));
typedef _Float16 v8h __attribute__((ext_vector_type(8)));
typedef float v4f __attribute__((ext_vector_type(4)));

#define EMB 256
#define VOCAB 50000

// ---------------- helpers ----------------
__device__ __forceinline__ float sigf(float x) {
    return 1.f / (1.f + __expf(-x));
}
__device__ __forceinline__ float tanhf_(float x) {
    float e = __expf(2.f * fabsf(x));
    float th = 1.f - 2.f / (e + 1.f);
    return copysignf(th, x);
}

// ---------------- K1: conv/BN stack (1 block, 384 threads) ----------------
__global__ __launch_bounds__(384) void k_conv(
        const float* __restrict__ board, const float* __restrict__ conv_w,
        const float* __restrict__ conv_b, const float* __restrict__ gamma,
        const float* __restrict__ beta, const float* __restrict__ p,
        float* __restrict__ d1_out) {
    __shared__ float cur[361];
    __shared__ float red1[8], red2[8];
    __shared__ float stats[2];
    const int t = threadIdx.x;
    const bool act = t < 361;
    const int r = t / 19, c = t % 19;
    float w[9];
#pragma unroll
    for (int k = 0; k < 9; ++k) w[k] = conv_w[k];
    const float cb = conv_b[0], ga = gamma[0], be = beta[0];
    float scales[8] = {p[0], p[1], p[2], p[3], p[4], p[5], p[6], 1.f};
    const int mode[8] = {2, 0, 1, 0, 1, 0, 1, 0};
    if (act) cur[t] = board[t];
    float d2r = 0.f;
    __syncthreads();
#pragma unroll
    for (int it = 0; it < 8; ++it) {
        float y = 0.f;
        if (act) {
#pragma unroll
            for (int di = 0; di < 3; ++di)
#pragma unroll
                for (int dj = 0; dj < 3; ++dj) {
                    int rr = r + di - 1, cc2 = c + dj - 1;
                    if (rr >= 0 && rr < 19 && cc2 >= 0 && cc2 < 19)
                        y += cur[rr * 19 + cc2] * w[di * 3 + dj];
                }
            y += cb;
        }
        float s1 = y, s2 = y * y;
        for (int m = 32; m; m >>= 1) {
            s1 += __shfl_xor(s1, m);
            s2 += __shfl_xor(s2, m);
        }
        const int wv = t >> 6;
        if ((t & 63) == 0) { red1[wv] = s1; red2[wv] = s2; }
        __syncthreads();
        if (t == 0) {
            float a = 0.f, b2 = 0.f;
            for (int i = 0; i < 6; ++i) { a += red1[i]; b2 += red2[i]; }
            float mu = a / 361.f;
            float var = b2 / 361.f - mu * mu;
            stats[0] = mu;
            stats[1] = rsqrtf(var + 1e-5f);
        }
        __syncthreads();
        float mu = stats[0], rs = stats[1];
        float v = ga * (y - mu) * rs + be;
        v *= scales[it];
        if (mode[it] == 1) v += d2r;
        v = fmaxf(v, 0.f);
        if (mode[it] != 0) d2r = v;
        if (act) cur[t] = v;
        __syncthreads();
    }
    if (act) d1_out[t] = cur[t];
}

// ---------------- K2: feat + W_sum(f16) + b_sum (81 blocks x 256) ----------------
__global__ __launch_bounds__(256) void k_prep(
        const float* __restrict__ Wlin, const float* __restrict__ blin,
        const float* __restrict__ d1,
        const float* __restrict__ Wih, const float* __restrict__ bih,
        const float* __restrict__ Whh, const float* __restrict__ bhh,
        float* __restrict__ feat, _Float16* __restrict__ wsum,
        float* __restrict__ bsum) {
    const int b = blockIdx.x, t = threadIdx.x;
    if (b < 16) {
        const int r = b * 16 + (t >> 4), kc = t & 15;
        const int k0 = kc * 23, k1 = (k0 + 23 < 361) ? k0 + 23 : 361;
        const float* wrow = Wlin + r * 361;
        float acc = 0.f;
        for (int k = k0; k < k1; ++k) acc += wrow[k] * d1[k];
        for (int m = 1; m < 16; m <<= 1) acc += __shfl_xor(acc, m);
        if (kc == 0) feat[r] = acc + blin[r];
    } else if (b < 80) {
        const int base = (b - 16) * 4096 + t;
#pragma unroll
        for (int i = 0; i < 16; ++i) {
            int idx = base + i * 256;
            wsum[idx] = (_Float16)(Wih[idx] + Whh[idx]);
        }
    } else {
        for (int i = t; i < 1024; i += 256) bsum[i] = bih[i] + bhh[i];
    }
}

// ---------------- K2b: gates0 = W_ih@feat + b_ih + b_hh (64 blocks x 256) -------
__global__ __launch_bounds__(256) void k_gates0(
        const float* __restrict__ Wih, const float* __restrict__ feat,
        const float* __restrict__ bih, const float* __restrict__ bhh,
        float* __restrict__ gates0) {
    const int r = blockIdx.x * 16 + (threadIdx.x >> 4), kc = threadIdx.x & 15;
    const float* wrow = Wih + r * 256 + kc * 16;
    const float* f = feat + kc * 16;
    float acc = 0.f;
#pragma unroll
    for (int k = 0; k < 16; ++k) acc += wrow[k] * f[k];
    for (int m = 1; m < 16; m <<= 1) acc += __shfl_xor(acc, m);
    if (kc == 0) gates0[r] = acc + bih[r] + bhh[r];
}

// ---------------- K3: 101-step LSTM chain via MFMA (1 block x 256) -----------
// Wave w (0..3) = gate w: owns W rows [w*256, w*256+256) = 16 row-tiles of
// 16x16x32-f16 MFMA, 8 k-tiles. A-frag residency:
//   kt 0..3 -> AGPRs (16 rt x 4 kt x v8h = 256 AGPR, "+a"-pinned ONCE;
//              MFMA reads AGPR natively - no move cost)
//   kt 4..5 -> VGPRs (128, "+v"-pinned once)
//   kt 6..7 -> LDS (128 KiB), ds_read_b128-staged per step
// B = h broadcast to all 16 cols: one v8h ds_read per k-tile (lane-group
// broadcast). C/D layout (verified in k_gemm): M-row = 4*(l>>4)+reg,
// N-col = l&15; all cols identical => masked gather (l&15)==0 writes gates
// to LDS; thread t then does pointwise for cell t.
__global__ __launch_bounds__(256, 1) void k_lstm(
        const _Float16* __restrict__ wsum, const float* __restrict__ bsum,
        const float* __restrict__ gates0, _Float16* __restrict__ Hg) {
    extern __shared__ char smem[];
    _Float16* Af  = (_Float16*)smem;            // 131072 B: A-frags kt 6,7
    char*     hb  = smem + 131072;              // 2 x 512 B h double-buffer
    float*    gbuf = (float*)(smem + 132096);   // 4096 B gate gather
    const int t = threadIdx.x;
    const int w = t >> 6;          // wave = gate index (i,f,g,o)
    const int l = t & 63;
    const int rit = l & 15;        // A row within tile
    const int kch = l >> 4;        // k-chunk 0..3 (8 f16 each)

    // --- load A fragments ---
    v8h aA[16][4];   // kt 0..3 -> AGPR
    v8h aV[16][2];   // kt 4..5 -> VGPR
#pragma unroll
    for (int j = 0; j < 16; ++j) {
        const _Float16* rbase = wsum + (w * 256 + j * 16 + rit) * 256 + kch * 8;
#pragma unroll
        for (int kt = 0; kt < 8; ++kt) {
            v8h f = *(const v8h*)(rbase + kt * 32);
            if (kt < 4)      aA[j][kt] = f;
            else if (kt < 6) aV[j][kt - 4] = f;
            else {
                const int rt = w * 16 + j;
                *(v8h*)(Af + (rt * 2 + (kt - 6)) * 512 + l * 8) = f;
            }
        }
    }
    // pin residency ONCE (no in-loop pins -> no per-step moves)
#pragma unroll
    for (int j = 0; j < 16; ++j) {
#pragma unroll
        for (int kt = 0; kt < 4; ++kt) asm("" : "+a"(aA[j][kt]));
#pragma unroll
        for (int kt = 0; kt < 2; ++kt) asm("" : "+v"(aV[j][kt]));
    }

    const float bs0 = bsum[t], bs1 = bsum[t + 256];
    const float bs2 = bsum[t + 512], bs3 = bsum[t + 768];

    float cst;
    {   // step 0 from precomputed gates0 (c=0 so f-gate drops out)
        float gi = gates0[t], gg = gates0[t + 512], go = gates0[t + 768];
        cst = sigf(gi) * tanhf_(gg);
        float h = sigf(go) * tanhf_(cst);
        *(_Float16*)(hb + t * 2) = (_Float16)h;     // buffer 0
        Hg[t] = (_Float16)h;
    }
    __syncthreads();

    for (int step = 1; step <= 100; ++step) {
        const _Float16* hr = (const _Float16*)(hb + ((step + 1) & 1) * 512);
        _Float16* hw = (_Float16*)(hb + (step & 1) * 512);
        // 4 groups of 4 row-tiles (keeps live regs low, 4 indep MFMA chains)
#pragma unroll
        for (int grp = 0; grp < 4; ++grp) {
            // B-frags (broadcast reads) + LDS A-frags for this group
            v8h bf[8];
#pragma unroll
            for (int kt = 0; kt < 8; ++kt)
                bf[kt] = *(const v8h*)(hr + kt * 32 + kch * 8);
            v8h a6[4], a7[4];
#pragma unroll
            for (int j4 = 0; j4 < 4; ++j4) {
                const int rt = w * 16 + grp * 4 + j4;
                a6[j4] = *(const v8h*)(Af + (rt * 2 + 0) * 512 + l * 8);
                a7[j4] = *(const v8h*)(Af + (rt * 2 + 1) * 512 + l * 8);
            }
            v4f acc[4];
#pragma unroll
            for (int j4 = 0; j4 < 4; ++j4) {
                acc[j4][0] = 0.f; acc[j4][1] = 0.f;
                acc[j4][2] = 0.f; acc[j4][3] = 0.f;
            }
#pragma unroll
            for (int kt = 0; kt < 4; ++kt)
#pragma unroll
                for (int j4 = 0; j4 < 4; ++j4)
                    acc[j4] = __builtin_amdgcn_mfma_f32_16x16x32_f16(
                        aA[grp * 4 + j4][kt], bf[kt], acc[j4], 0, 0, 0);
#pragma unroll
            for (int kt = 0; kt < 2; ++kt)
#pragma unroll
                for (int j4 = 0; j4 < 4; ++j4)
                    acc[j4] = __builtin_amdgcn_mfma_f32_16x16x32_f16(
                        aV[grp * 4 + j4][kt], bf[4 + kt], acc[j4], 0, 0, 0);
#pragma unroll
            for (int j4 = 0; j4 < 4; ++j4)
                acc[j4] = __builtin_amdgcn_mfma_f32_16x16x32_f16(
                    a6[j4], bf[6], acc[j4], 0, 0, 0);
#pragma unroll
            for (int j4 = 0; j4 < 4; ++j4)
                acc[j4] = __builtin_amdgcn_mfma_f32_16x16x32_f16(
                    a7[j4], bf[7], acc[j4], 0, 0, 0);
            // gather col-0 quads: lanes {0,16,32,48} hold rows 4*kch+reg
#pragma unroll
            for (int j4 = 0; j4 < 4; ++j4) {
                if (rit == 0) {
                    const int c0 = (grp * 4 + j4) * 16 + kch * 4;
                    *(v4f*)&gbuf[w * 256 + c0] = acc[j4];
                }
            }
        }
        __syncthreads();
        // pointwise: thread t = cell t
        float gi = gbuf[t]       + bs0;
        float gf = gbuf[256 + t] + bs1;
        float gg = gbuf[512 + t] + bs2;
        float go = gbuf[768 + t] + bs3;
        cst = sigf(gf) * cst + sigf(gi) * tanhf_(gg);
        float h = sigf(go) * tanhf_(cst);
        hw[t] = (_Float16)h;
        Hg[step * 256 + t] = (_Float16)h;
        __syncthreads();
    }
}

// ---------------- K4: logits GEMM [50048x256]x[256x112] via MFMA f16 ----------
// A-loads hoisted: all 16 in flight before the MFMA chain (latency fix).
__global__ __launch_bounds__(256) void k_gemm(
        const float* __restrict__ Wdec, const float* __restrict__ bdec,
        const _Float16* __restrict__ Hg, float* __restrict__ out) {
    __shared__ _Float16 Hl[112 * 264];
    const int t = threadIdx.x;
    float4 z; z.x = 0.f; z.y = 0.f; z.z = 0.f; z.w = 0.f;
    for (int i = t; i < 3696; i += 256) ((float4*)Hl)[i] = z;
    __syncthreads();
    for (int i = t; i < 101 * 32; i += 256) {
        int row = i >> 5, kc = i & 31;
        float4 v = ((const float4*)Hg)[i];
        *(float4*)(Hl + row * 264 + kc * 8) = v;
    }
    __syncthreads();

    const int l = t & 63, wv = t >> 6;
    const int mrow = blockIdx.x * 64 + wv * 16 + (l & 15);
    const int mcl = (mrow < VOCAB) ? mrow : (VOCAB - 1);
    const float* arow = Wdec + (size_t)mcl * 256 + ((l >> 4) << 3);
    const _Float16* brow = Hl + (l & 15) * 264 + ((l >> 4) << 3);

    // hoist ALL A loads (16 x 16B in flight)
    float4 a0[8], a1[8];
#pragma unroll
    for (int ks = 0; ks < 8; ++ks) {
        a0[ks] = *(const float4*)(arow + ks * 32);
        a1[ks] = *(const float4*)(arow + ks * 32 + 4);
    }

    v4f acc[7];
#pragma unroll
    for (int nt = 0; nt < 7; ++nt) {
#pragma unroll
        for (int j = 0; j < 4; ++j) acc[nt][j] = 0.f;
    }
#pragma unroll
    for (int ks = 0; ks < 8; ++ks) {
        v8h af;
        af[0] = (_Float16)a0[ks].x; af[1] = (_Float16)a0[ks].y;
        af[2] = (_Float16)a0[ks].z; af[3] = (_Float16)a0[ks].w;
        af[4] = (_Float16)a1[ks].x; af[5] = (_Float16)a1[ks].y;
        af[6] = (_Float16)a1[ks].z; af[7] = (_Float16)a1[ks].w;
#pragma unroll
        for (int nt = 0; nt < 7; ++nt) {
            v8h bf = *(const v8h*)(brow + nt * 16 * 264 + ks * 32);
            acc[nt] = __builtin_amdgcn_mfma_f32_16x16x32_f16(af, bf, acc[nt], 0, 0, 0);
        }
    }
    const int rowq = blockIdx.x * 64 + wv * 16 + ((l >> 4) << 2);
    if (rowq < VOCAB) {
        float4 bd = *(const float4*)(bdec + rowq);
#pragma unroll
        for (int nt = 0; nt < 7; ++nt) {
            int tt = nt * 16 + (l & 15);
            if (tt <= 100) {
                float4 v;
                v.x = fmaxf(acc[nt][0] + bd.x, 0.f);
                v.y = fmaxf(acc[nt][1] + bd.y, 0.f);
                v.z = fmaxf(acc[nt][2] + bd.z, 0.f);
                v.w = fmaxf(acc[nt][3] + bd.w, 0.f);
                *(float4*)(out + (size_t)tt * VOCAB + rowq) = v;
            }
        }
    }
}

// ---------------- launch ----------------
extern "C" void kernel_launch(void* const* d_in, const int* in_sizes, int n_in,
                              void* d_out, int out_size, void* d_ws, size_t ws_size,
                              hipStream_t stream) {
    const float* board  = (const float*)d_in[0];
    const float* conv_w = (const float*)d_in[1];
    const float* conv_b = (const float*)d_in[2];
    const float* bn_g   = (const float*)d_in[3];
    const float* bn_b   = (const float*)d_in[4];
    const float* p      = (const float*)d_in[5];
    const float* Wlin   = (const float*)d_in[6];
    const float* blin   = (const float*)d_in[7];
    const float* Wih    = (const float*)d_in[8];
    const float* bih    = (const float*)d_in[9];
    const float* Whh    = (const float*)d_in[10];
    const float* bhh    = (const float*)d_in[11];
    const float* Wdec   = (const float*)d_in[12];
    const float* bdec   = (const float*)d_in[13];
    float* out = (float*)d_out;
    char* ws = (char*)d_ws;

    _Float16* wsum  = (_Float16*)(ws);             // 524288 B
    _Float16* Hg    = (_Float16*)(ws + 524288);    // 51712 B
    float* d1       = (float*)(ws + 576512);       // 1444 B
    float* feat     = (float*)(ws + 578560);       // 1024 B
    float* gates0   = (float*)(ws + 579584);       // 4096 B
    float* bsum     = (float*)(ws + 583680);       // 4096 B

    k_conv<<<1, 384, 0, stream>>>(board, conv_w, conv_b, bn_g, bn_b, p, d1);
    k_prep<<<81, 256, 0, stream>>>(Wlin, blin, d1, Wih, bih, Whh, bhh, feat, wsum, bsum);
    k_gates0<<<64, 256, 0, stream>>>(Wih, feat, bih, bhh, gates0);
    k_lstm<<<1, 256, 136192, stream>>>(wsum, bsum, gates0, Hg);
    k_gemm<<<782, 256, 0, stream>>>(Wdec, bdec, Hg, out);
}